// Round 1
// baseline (1564.103 us; speedup 1.0000x reference)
//
#include <hip/hip_runtime.h>

// ---------------------------------------------------------------------------
// GATv2 x4 + MLP readout.  CSR-by-dst build once per call, then per layer:
//   k_transform: xl = x@Wl+bl, xr = x@Wr+br       (LDS-staged weights)
//   k_score:     per-node wave computes edge scores + running max
//   k_aggr:      per-node wave: softmax denom + weighted gather-sum
// Readout: f64-atomic mean + tiny single-block MLP.
// ---------------------------------------------------------------------------

__global__ void k_hist(const int* __restrict__ dst, int* __restrict__ deg, int E) {
  int e = blockIdx.x * blockDim.x + threadIdx.x;
  if (e < E) atomicAdd(&deg[dst[e]], 1);
}

// exclusive prefix sum over n ints, single workgroup of 1024
__global__ void k_scan(const int* __restrict__ deg, int* __restrict__ rowptr, int n) {
  __shared__ int wsum[16];
  __shared__ int carry_s;
  int tid = threadIdx.x;
  int lane = tid & 63;
  int wv = tid >> 6;
  if (tid == 0) carry_s = 0;
  __syncthreads();
  for (int base = 0; base < n; base += 1024) {
    int i = base + tid;
    int v = (i < n) ? deg[i] : 0;
    int x = v;
    #pragma unroll
    for (int off = 1; off < 64; off <<= 1) {
      int t = __shfl_up(x, off, 64);
      if (lane >= off) x += t;
    }
    if (lane == 63) wsum[wv] = x;
    __syncthreads();
    if (wv == 0 && lane < 16) {
      int w = wsum[lane];
      int y = w;
      #pragma unroll
      for (int off = 1; off < 16; off <<= 1) {
        int t = __shfl_up(y, off, 16);
        if (lane >= off) y += t;
      }
      wsum[lane] = y - w;  // exclusive prefix of wave sums
    }
    __syncthreads();
    int excl = carry_s + wsum[wv] + (x - v);
    if (i < n) rowptr[i] = excl;
    __syncthreads();
    if (tid == 1023) carry_s = excl + v;  // carry + chunk total
    __syncthreads();
  }
  if (tid == 0) rowptr[n] = carry_s;
}

__global__ void k_fill(const int* __restrict__ src, const int* __restrict__ dst,
                       const float* __restrict__ ea_in, const int* __restrict__ rowptr,
                       int* __restrict__ cursor, int* __restrict__ srcs,
                       float* __restrict__ ea_out, int E) {
  int e = blockIdx.x * blockDim.x + threadIdx.x;
  if (e < E) {
    int d = dst[e];
    int pos = rowptr[d] + atomicAdd(&cursor[d], 1);
    srcs[pos] = src[e];
    ea_out[pos] = ea_in[e];
  }
}

// xl = x @ Wl + bl ; xr = x @ Wr + br   (dout = 64). 4 nodes per 256-thr block.
template <int DIN>
__global__ void __launch_bounds__(256) k_transform(
    const float* __restrict__ x, const float* __restrict__ Wl, const float* __restrict__ bl,
    const float* __restrict__ Wr, const float* __restrict__ br,
    float* __restrict__ xl, float* __restrict__ xr, int nNodes) {
  __shared__ float sWl[DIN * 64];
  __shared__ float sWr[DIN * 64];
  __shared__ float sx[4][DIN];
  int tid = threadIdx.x;
  for (int i = tid; i < DIN * 64; i += 256) { sWl[i] = Wl[i]; sWr[i] = Wr[i]; }
  int nb = blockIdx.x * 4;
  for (int i = tid; i < 4 * DIN; i += 256) {
    int nn = nb + i / DIN;
    sx[i / DIN][i % DIN] = (nn < nNodes) ? x[(size_t)nn * DIN + (i % DIN)] : 0.f;
  }
  __syncthreads();
  int node = nb + (tid >> 6);
  int c = tid & 63;
  if (node < nNodes) {
    float al = bl[c], ar = br[c];
    const float* xrow = sx[tid >> 6];
    #pragma unroll
    for (int k = 0; k < DIN; k++) {
      float xv = xrow[k];
      al = fmaf(xv, sWl[k * 64 + c], al);
      ar = fmaf(xv, sWr[k * 64 + c], ar);
    }
    xl[(size_t)node * 64 + c] = al;
    xr[(size_t)node * 64 + c] = ar;
  }
}

// one wave per node: scores for its in-edges (CSR order) + running max
__global__ void __launch_bounds__(256) k_score(
    const float* __restrict__ xl, const float* __restrict__ xr,
    const int* __restrict__ rowptr, const int* __restrict__ srcs,
    const float* __restrict__ eattr, const float* __restrict__ We,
    const float* __restrict__ att, float* __restrict__ score,
    float* __restrict__ marr, int nNodes) {
  int n = (blockIdx.x * blockDim.x + threadIdx.x) >> 6;
  int lane = threadIdx.x & 63;
  if (n >= nNodes) return;
  int s0 = rowptr[n], s1 = rowptr[n + 1];
  float rc = xr[(size_t)n * 64 + lane];
  float ac = att[lane];
  float wec = We[lane];
  float m = -3.0e38f;
  for (int kb = s0; kb < s1; kb += 64) {
    int kk = kb + lane;
    int sv = 0;
    float ev = 0.f;
    if (kk < s1) { sv = srcs[kk]; ev = eattr[kk]; }
    int cnt = min(64, s1 - kb);
    float myscore = 0.f;
    for (int j = 0; j < cnt; j++) {
      int s = __shfl(sv, j, 64);
      float ea = __shfl(ev, j, 64);
      float v = xl[(size_t)s * 64 + lane] + rc + ea * wec;
      v = (v >= 0.f) ? v : 0.2f * v;   // leaky_relu 0.2
      float p = v * ac;
      #pragma unroll
      for (int o = 32; o > 0; o >>= 1) p += __shfl_xor(p, o, 64);
      if (lane == j) myscore = p;
      m = fmaxf(m, p);
    }
    if (kk < s1) score[kk] = myscore;  // coalesced
  }
  if (lane == 0) marr[n] = m;
}

// one wave per node: softmax denom + out[c] = sum alpha * xl[src][c]
__global__ void __launch_bounds__(256) k_aggr(
    const float* __restrict__ xl, const int* __restrict__ rowptr,
    const int* __restrict__ srcs, const float* __restrict__ score,
    const float* __restrict__ marr, const float* __restrict__ bo,
    float* __restrict__ xout, int nNodes) {
  int n = (blockIdx.x * blockDim.x + threadIdx.x) >> 6;
  int lane = threadIdx.x & 63;
  if (n >= nNodes) return;
  int s0 = rowptr[n], s1 = rowptr[n + 1];
  float m = marr[n];
  float dsum = 0.f;
  for (int kk = s0 + lane; kk < s1; kk += 64) dsum += expf(score[kk] - m);
  #pragma unroll
  for (int o = 32; o > 0; o >>= 1) dsum += __shfl_xor(dsum, o, 64);
  float inv = 1.f / (dsum + 1e-16f);
  float out = 0.f;
  for (int kb = s0; kb < s1; kb += 64) {
    int kk = kb + lane;
    int sv = 0;
    float al = 0.f;
    if (kk < s1) { sv = srcs[kk]; al = expf(score[kk] - m) * inv; }
    int cnt = min(64, s1 - kb);
    for (int j = 0; j < cnt; j++) {
      int s = __shfl(sv, j, 64);
      float a = __shfl(al, j, 64);
      out = fmaf(a, xl[(size_t)s * 64 + lane], out);
    }
  }
  out += bo[lane];
  xout[(size_t)n * 64 + lane] = fmaxf(out, 0.f);  // relu after every conv
}

__global__ void k_mean(const float* __restrict__ x, double* __restrict__ meanbuf, int nNodes) {
  __shared__ float sacc[256];
  int lane = threadIdx.x & 63;
  int wv = threadIdx.x >> 6;
  int gw = blockIdx.x * 4 + wv;
  int stride = gridDim.x * 4;
  float acc = 0.f;
  for (int n = gw; n < nNodes; n += stride) acc += x[(size_t)n * 64 + lane];
  sacc[threadIdx.x] = acc;
  __syncthreads();
  if (threadIdx.x < 64) {
    float a = sacc[threadIdx.x] + sacc[threadIdx.x + 64] + sacc[threadIdx.x + 128] + sacc[threadIdx.x + 192];
    atomicAdd(&meanbuf[lane], (double)a);
  }
}

__global__ void k_mlp(const double* __restrict__ meanbuf,
                      const float* __restrict__ Wm1, const float* __restrict__ bm1,
                      const float* __restrict__ Wm2, const float* __restrict__ bm2,
                      const float* __restrict__ Wm3, const float* __restrict__ bm3,
                      float* __restrict__ out, double invN) {
  __shared__ float xm[64];
  __shared__ float h1[32];
  __shared__ float h2[16];
  int t = threadIdx.x;
  xm[t] = (float)(meanbuf[t] * invN);
  __syncthreads();
  if (t < 32) {
    float a = bm1[t];
    for (int c = 0; c < 64; c++) a = fmaf(xm[c], Wm1[c * 32 + t], a);
    h1[t] = fmaxf(a, 0.f);
  }
  __syncthreads();
  if (t < 16) {
    float a = bm2[t];
    for (int c = 0; c < 32; c++) a = fmaf(h1[c], Wm2[c * 16 + t], a);
    h2[t] = fmaxf(a, 0.f);
  }
  __syncthreads();
  if (t == 0) {
    float a = bm3[0];
    for (int c = 0; c < 16; c++) a = fmaf(h2[c], Wm3[c], a);
    out[0] = a;
  }
}

extern "C" void kernel_launch(void* const* d_in, const int* in_sizes, int n_in,
                              void* d_out, int out_size, void* d_ws, size_t ws_size,
                              hipStream_t stream) {
  (void)n_in; (void)out_size; (void)ws_size;
  const int N = in_sizes[0] / 36;   // 50000
  const int E = in_sizes[1];        // 1600000

  const float* feat = (const float*)d_in[0];
  const float* eat  = (const float*)d_in[1];
  const int*   eidx = (const int*)d_in[2];
  const int* src = eidx;
  const int* dst = eidx + E;

  const float* L[4][7];  // Wl, bl, Wr, br, We, att, bo
  for (int l = 0; l < 4; l++)
    for (int j = 0; j < 7; j++) L[l][j] = (const float*)d_in[3 + l * 7 + j];
  const float* Wm1 = (const float*)d_in[31];
  const float* bm1 = (const float*)d_in[32];
  const float* Wm2 = (const float*)d_in[33];
  const float* bm2 = (const float*)d_in[34];
  const float* Wm3 = (const float*)d_in[35];
  const float* bm3 = (const float*)d_in[36];

  // workspace layout (512B aligned)
  char* ws = (char*)d_ws;
  size_t off = 0;
  auto alloc = [&](size_t bytes) {
    off = (off + 511) & ~(size_t)511;
    void* p = ws + off;
    off += bytes;
    return p;
  };
  int*    deg     = (int*)alloc((size_t)N * 4);
  int*    cursor  = (int*)alloc((size_t)N * 4);
  double* meanbuf = (double*)alloc(64 * 8);
  size_t zero_bytes = off;  // deg + cursor + meanbuf
  int*    rowptr  = (int*)alloc((size_t)(N + 1) * 4);
  int*    srcs    = (int*)alloc((size_t)E * 4);
  float*  eattrw  = (float*)alloc((size_t)E * 4);
  float*  score   = (float*)alloc((size_t)E * 4);
  float*  marr    = (float*)alloc((size_t)N * 4);
  float*  xA      = (float*)alloc((size_t)N * 64 * 4);  // xl
  float*  xB      = (float*)alloc((size_t)N * 64 * 4);  // xr
  float*  xC      = (float*)alloc((size_t)N * 64 * 4);  // layer output / next input

  hipMemsetAsync(d_ws, 0, zero_bytes, stream);

  int egrid = (E + 255) / 256;
  int ngrid = (N + 3) / 4;  // 4 nodes (waves) per 256-thr block

  k_hist<<<egrid, 256, 0, stream>>>(dst, deg, E);
  k_scan<<<1, 1024, 0, stream>>>(deg, rowptr, N);
  k_fill<<<egrid, 256, 0, stream>>>(src, dst, eat, rowptr, cursor, srcs, eattrw, E);

  for (int l = 0; l < 4; l++) {
    if (l == 0)
      k_transform<36><<<ngrid, 256, 0, stream>>>(feat, L[0][0], L[0][1], L[0][2], L[0][3], xA, xB, N);
    else
      k_transform<64><<<ngrid, 256, 0, stream>>>(xC, L[l][0], L[l][1], L[l][2], L[l][3], xA, xB, N);
    k_score<<<ngrid, 256, 0, stream>>>(xA, xB, rowptr, srcs, eattrw, L[l][4], L[l][5], score, marr, N);
    k_aggr<<<ngrid, 256, 0, stream>>>(xA, rowptr, srcs, score, marr, L[l][6], xC, N);
  }

  k_mean<<<256, 256, 0, stream>>>(xC, meanbuf, N);
  k_mlp<<<1, 64, 0, stream>>>(meanbuf, Wm1, bm1, Wm2, bm2, Wm3, bm3, (float*)d_out, 1.0 / (double)N);
}

// Round 2
// 1149.167 us; speedup vs baseline: 1.3611x; 1.3611x over previous
//
#include <hip/hip_runtime.h>

// ---------------------------------------------------------------------------
// GATv2 x4 + MLP readout.  CSR-by-dst build once per call, then per layer:
//   k_transform: xl = x@Wl+bl, xr = x@Wr+br       (LDS-staged weights)
//   k_edge:      fused score + online-softmax + aggregate, one wave per node.
//     Per 64-edge chunk: global_load_lds stages xl[src] rows into a padded
//     per-wave LDS tile (stride 65 -> 2-way bank alias = free). Scores are
//     computed lane=edge (zero cross-lane ops, scalar loads for xr/att/We),
//     one expf per chunk, aggregation lane=channel with v_readlane alphas.
// Readout: f64-atomic mean + tiny single-block MLP.
// ---------------------------------------------------------------------------

__device__ __forceinline__ float readlane_f(float v, int l) {
  return __int_as_float(__builtin_amdgcn_readlane(__float_as_int(v), l));
}
__device__ __forceinline__ int rfl(int v) { return __builtin_amdgcn_readfirstlane(v); }

__device__ __forceinline__ void row_to_lds(const float* g, float* l) {
  __builtin_amdgcn_global_load_lds((const __attribute__((address_space(1))) void*)g,
                                   (__attribute__((address_space(3))) void*)l,
                                   4, 0, 0);
}

__global__ void k_hist(const int* __restrict__ dst, int* __restrict__ deg, int E) {
  int e = blockIdx.x * blockDim.x + threadIdx.x;
  if (e < E) atomicAdd(&deg[dst[e]], 1);
}

// exclusive prefix sum over n ints, single workgroup of 1024
__global__ void k_scan(const int* __restrict__ deg, int* __restrict__ rowptr, int n) {
  __shared__ int wsum[16];
  __shared__ int carry_s;
  int tid = threadIdx.x;
  int lane = tid & 63;
  int wv = tid >> 6;
  if (tid == 0) carry_s = 0;
  __syncthreads();
  for (int base = 0; base < n; base += 1024) {
    int i = base + tid;
    int v = (i < n) ? deg[i] : 0;
    int x = v;
    #pragma unroll
    for (int off = 1; off < 64; off <<= 1) {
      int t = __shfl_up(x, off, 64);
      if (lane >= off) x += t;
    }
    if (lane == 63) wsum[wv] = x;
    __syncthreads();
    if (wv == 0 && lane < 16) {
      int w = wsum[lane];
      int y = w;
      #pragma unroll
      for (int off = 1; off < 16; off <<= 1) {
        int t = __shfl_up(y, off, 16);
        if (lane >= off) y += t;
      }
      wsum[lane] = y - w;  // exclusive prefix of wave sums
    }
    __syncthreads();
    int excl = carry_s + wsum[wv] + (x - v);
    if (i < n) rowptr[i] = excl;
    __syncthreads();
    if (tid == 1023) carry_s = excl + v;  // carry + chunk total
    __syncthreads();
  }
  if (tid == 0) rowptr[n] = carry_s;
}

// permute (src, edge_attr) into CSR-by-dst order as packed int2
__global__ void k_fill(const int* __restrict__ src, const int* __restrict__ dst,
                       const float* __restrict__ ea_in, const int* __restrict__ rowptr,
                       int* __restrict__ cursor, int2* __restrict__ pairs, int E) {
  int e = blockIdx.x * blockDim.x + threadIdx.x;
  if (e < E) {
    int d = dst[e];
    int pos = rowptr[d] + atomicAdd(&cursor[d], 1);
    pairs[pos] = make_int2(src[e], __float_as_int(ea_in[e]));
  }
}

// xl = x @ Wl + bl ; xr = x @ Wr + br   (dout = 64). 4 nodes per 256-thr block.
template <int DIN>
__global__ void __launch_bounds__(256) k_transform(
    const float* __restrict__ x, const float* __restrict__ Wl, const float* __restrict__ bl,
    const float* __restrict__ Wr, const float* __restrict__ br,
    float* __restrict__ xl, float* __restrict__ xr, int nNodes) {
  __shared__ float sWl[DIN * 64];
  __shared__ float sWr[DIN * 64];
  __shared__ float sx[4][DIN];
  int tid = threadIdx.x;
  for (int i = tid; i < DIN * 64; i += 256) { sWl[i] = Wl[i]; sWr[i] = Wr[i]; }
  int nb = blockIdx.x * 4;
  for (int i = tid; i < 4 * DIN; i += 256) {
    int nn = nb + i / DIN;
    sx[i / DIN][i % DIN] = (nn < nNodes) ? x[(size_t)nn * DIN + (i % DIN)] : 0.f;
  }
  __syncthreads();
  int node = nb + (tid >> 6);
  int c = tid & 63;
  if (node < nNodes) {
    float al = bl[c], ar = br[c];
    const float* xrow = sx[tid >> 6];
    #pragma unroll
    for (int k = 0; k < DIN; k++) {
      float xv = xrow[k];
      al = fmaf(xv, sWl[k * 64 + c], al);
      ar = fmaf(xv, sWr[k * 64 + c], ar);
    }
    xl[(size_t)node * 64 + c] = al;
    xr[(size_t)node * 64 + c] = ar;
  }
}

// Fused score + online softmax + aggregate. One wave per node, block = 128.
__global__ void __launch_bounds__(128) k_edge(
    const float* __restrict__ xl, const float* __restrict__ xr,
    const int* __restrict__ rowptr, const int2* __restrict__ pairs,
    const float* __restrict__ We, const float* __restrict__ att,
    const float* __restrict__ bo, float* __restrict__ xout, int nNodes) {
  __shared__ float tile[2][64 * 65];  // per-wave tile, stride 65 (pad)
  int lane = threadIdx.x & 63;
  int wv = rfl((int)(threadIdx.x >> 6));
  int n = rfl(blockIdx.x * 2 + wv);
  if (n >= nNodes) return;
  float* tw = tile[wv];
  int s0 = rfl(rowptr[n]);
  int s1 = rfl(rowptr[n + 1]);
  const float* xrn = xr + (size_t)n * 64;

  float m = -3.0e38f, d = 0.f, acc0 = 0.f, acc1 = 0.f;

  for (int kb = s0; kb < s1; kb += 64) {
    int cnt = rfl(min(64, s1 - kb));
    int2 pv = make_int2(0, 0);
    if (kb + lane < s1) pv = pairs[kb + lane];
    float ea = __int_as_float(pv.y);

    // ---- phase A: stage xl rows of this chunk into LDS (async, 1 instr/row)
    for (int j = 0; j < cnt; ++j) {
      int s = __builtin_amdgcn_readlane(pv.x, j);
      row_to_lds(xl + (size_t)s * 64 + lane, tw + j * 65);
    }
    for (int j = cnt; j < 64; ++j) tw[j * 65 + lane] = 0.f;  // pad rows -> safe
    __builtin_amdgcn_s_waitcnt(0);

    // ---- phase B: score, lane = edge.  xr/We/att are wave-uniform -> s_load
    float sc = 0.f;
    #pragma unroll 16
    for (int c = 0; c < 64; ++c) {
      float tv = tw[lane * 65 + c];                 // 2-way bank alias: free
      float v = tv + xrn[c] + ea * We[c];
      v = fmaxf(v, 0.2f * v);                       // leaky_relu 0.2
      sc = fmaf(att[c], v, sc);
    }
    sc = (lane < cnt) ? sc : -3.0e38f;

    // ---- online softmax (one expf per chunk, 12 shuffles total)
    float mc = sc;
    #pragma unroll
    for (int o = 32; o > 0; o >>= 1) mc = fmaxf(mc, __shfl_xor(mc, o, 64));
    float newm = fmaxf(m, mc);
    float r = expf(m - newm);          // 1.0 when max unchanged; 0 on first chunk
    float alpha = expf(sc - newm);     // 0 for padded lanes
    float ds = alpha;
    #pragma unroll
    for (int o = 32; o > 0; o >>= 1) ds += __shfl_xor(ds, o, 64);
    d = d * r + ds;
    acc0 *= r;
    acc1 *= r;
    m = newm;

    // ---- phase C: aggregate, lane = channel (fixed 64 iters, padded rows = 0)
    #pragma unroll
    for (int j = 0; j < 64; j += 2) {
      acc0 = fmaf(readlane_f(alpha, j),     tw[j * 65 + lane],       acc0);
      acc1 = fmaf(readlane_f(alpha, j + 1), tw[(j + 1) * 65 + lane], acc1);
    }
  }

  float inv = 1.f / (d + 1e-16f);
  float out = (acc0 + acc1) * inv + bo[lane];
  xout[(size_t)n * 64 + lane] = fmaxf(out, 0.f);  // relu after every conv
}

__global__ void k_mean(const float* __restrict__ x, double* __restrict__ meanbuf, int nNodes) {
  __shared__ float sacc[256];
  int lane = threadIdx.x & 63;
  int wv = threadIdx.x >> 6;
  int gw = blockIdx.x * 4 + wv;
  int stride = gridDim.x * 4;
  float acc = 0.f;
  for (int n = gw; n < nNodes; n += stride) acc += x[(size_t)n * 64 + lane];
  sacc[threadIdx.x] = acc;
  __syncthreads();
  if (threadIdx.x < 64) {
    float a = sacc[threadIdx.x] + sacc[threadIdx.x + 64] + sacc[threadIdx.x + 128] + sacc[threadIdx.x + 192];
    atomicAdd(&meanbuf[lane], (double)a);
  }
}

__global__ void k_mlp(const double* __restrict__ meanbuf,
                      const float* __restrict__ Wm1, const float* __restrict__ bm1,
                      const float* __restrict__ Wm2, const float* __restrict__ bm2,
                      const float* __restrict__ Wm3, const float* __restrict__ bm3,
                      float* __restrict__ out, double invN) {
  __shared__ float xm[64];
  __shared__ float h1[32];
  __shared__ float h2[16];
  int t = threadIdx.x;
  xm[t] = (float)(meanbuf[t] * invN);
  __syncthreads();
  if (t < 32) {
    float a = bm1[t];
    for (int c = 0; c < 64; c++) a = fmaf(xm[c], Wm1[c * 32 + t], a);
    h1[t] = fmaxf(a, 0.f);
  }
  __syncthreads();
  if (t < 16) {
    float a = bm2[t];
    for (int c = 0; c < 32; c++) a = fmaf(h1[c], Wm2[c * 16 + t], a);
    h2[t] = fmaxf(a, 0.f);
  }
  __syncthreads();
  if (t == 0) {
    float a = bm3[0];
    for (int c = 0; c < 16; c++) a = fmaf(h2[c], Wm3[c], a);
    out[0] = a;
  }
}

extern "C" void kernel_launch(void* const* d_in, const int* in_sizes, int n_in,
                              void* d_out, int out_size, void* d_ws, size_t ws_size,
                              hipStream_t stream) {
  (void)n_in; (void)out_size; (void)ws_size;
  const int N = in_sizes[0] / 36;   // 50000
  const int E = in_sizes[1];        // 1600000

  const float* feat = (const float*)d_in[0];
  const float* eat  = (const float*)d_in[1];
  const int*   eidx = (const int*)d_in[2];
  const int* src = eidx;
  const int* dst = eidx + E;

  const float* L[4][7];  // Wl, bl, Wr, br, We, att, bo
  for (int l = 0; l < 4; l++)
    for (int j = 0; j < 7; j++) L[l][j] = (const float*)d_in[3 + l * 7 + j];
  const float* Wm1 = (const float*)d_in[31];
  const float* bm1 = (const float*)d_in[32];
  const float* Wm2 = (const float*)d_in[33];
  const float* bm2 = (const float*)d_in[34];
  const float* Wm3 = (const float*)d_in[35];
  const float* bm3 = (const float*)d_in[36];

  // workspace layout (512B aligned)
  char* ws = (char*)d_ws;
  size_t off = 0;
  auto alloc = [&](size_t bytes) {
    off = (off + 511) & ~(size_t)511;
    void* p = ws + off;
    off += bytes;
    return p;
  };
  int*    deg     = (int*)alloc((size_t)N * 4);
  int*    cursor  = (int*)alloc((size_t)N * 4);
  double* meanbuf = (double*)alloc(64 * 8);
  size_t zero_bytes = off;  // deg + cursor + meanbuf
  int*    rowptr  = (int*)alloc((size_t)(N + 1) * 4);
  int2*   pairs   = (int2*)alloc((size_t)E * 8);
  float*  xA      = (float*)alloc((size_t)N * 64 * 4);  // xl
  float*  xB      = (float*)alloc((size_t)N * 64 * 4);  // xr
  float*  xC      = (float*)alloc((size_t)N * 64 * 4);  // layer output / next input

  hipMemsetAsync(d_ws, 0, zero_bytes, stream);

  int egrid = (E + 255) / 256;
  int tgrid = (N + 3) / 4;   // k_transform: 4 nodes per 256-thr block
  int ngrid = (N + 1) / 2;   // k_edge: 2 nodes (waves) per 128-thr block

  k_hist<<<egrid, 256, 0, stream>>>(dst, deg, E);
  k_scan<<<1, 1024, 0, stream>>>(deg, rowptr, N);
  k_fill<<<egrid, 256, 0, stream>>>(src, dst, eat, rowptr, cursor, pairs, E);

  for (int l = 0; l < 4; l++) {
    if (l == 0)
      k_transform<36><<<tgrid, 256, 0, stream>>>(feat, L[0][0], L[0][1], L[0][2], L[0][3], xA, xB, N);
    else
      k_transform<64><<<tgrid, 256, 0, stream>>>(xC, L[l][0], L[l][1], L[l][2], L[l][3], xA, xB, N);
    k_edge<<<ngrid, 128, 0, stream>>>(xA, xB, rowptr, pairs, L[l][4], L[l][5], L[l][6], xC, N);
  }

  k_mean<<<256, 256, 0, stream>>>(xC, meanbuf, N);
  k_mlp<<<1, 64, 0, stream>>>(meanbuf, Wm1, bm1, Wm2, bm2, Wm3, bm3, (float*)d_out, 1.0 / (double)N);
}

// Round 3
// 874.496 us; speedup vs baseline: 1.7886x; 1.3141x over previous
//
#include <hip/hip_runtime.h>

// ---------------------------------------------------------------------------
// GATv2 x4 + MLP readout.  CSR-by-dst build once per call, then per layer:
//   k_transform: xl = x@Wl+bl, xr = x@Wr+br  (16 nodes/block, float4 acc)
//   k_edge: fused score + online-softmax + aggregate. One wave per NODE,
//     chunk = 32 edges (avg deg = 32).  Lane = 2*e + h: each lane dots 32
//     channels of edge e (ds_read_b128 from a 68-stride tile), pair-combined
//     with one shfl_xor(1).  Softmax over strides {2..32}.  Aggregate is
//     lane=channel, fixed 32 iters; padded edges have alpha = exactly 0.
// CSR scan is 3-kernel parallel (blockwise reduce -> 1-wave scan -> rescan).
// Readout: f64-atomic mean + tiny single-block MLP.
// ---------------------------------------------------------------------------

__device__ __forceinline__ float readlane_f(float v, int l) {
  return __int_as_float(__builtin_amdgcn_readlane(__float_as_int(v), l));
}
__device__ __forceinline__ int rfl(int v) { return __builtin_amdgcn_readfirstlane(v); }

__device__ __forceinline__ void row_to_lds(const float* g, float* l) {
  __builtin_amdgcn_global_load_lds((const __attribute__((address_space(1))) void*)g,
                                   (__attribute__((address_space(3))) void*)l,
                                   4, 0, 0);
}

__global__ void k_hist(const int* __restrict__ dst, int* __restrict__ deg, int E) {
  int e = blockIdx.x * blockDim.x + threadIdx.x;
  if (e < E) atomicAdd(&deg[dst[e]], 1);
}

// ---- parallel exclusive scan over n ints: A (block sums), B (scan sums), C
__global__ void __launch_bounds__(256) k_scanA(const int* __restrict__ deg,
                                               int* __restrict__ bsum, int n) {
  __shared__ int ws[4];
  int tid = threadIdx.x, lane = tid & 63, wv = tid >> 6;
  int base = blockIdx.x * 1024 + tid;
  int s = 0;
  #pragma unroll
  for (int k = 0; k < 4; k++) {
    int i = base + k * 256;
    if (i < n) s += deg[i];
  }
  #pragma unroll
  for (int o = 32; o > 0; o >>= 1) s += __shfl_xor(s, o, 64);
  if (lane == 0) ws[wv] = s;
  __syncthreads();
  if (tid == 0) bsum[blockIdx.x] = ws[0] + ws[1] + ws[2] + ws[3];
}

__global__ void k_scanB(const int* __restrict__ bsum, int* __restrict__ boffs,
                        int* __restrict__ rowptr, int nb, int n) {
  int lane = threadIdx.x;  // 64 threads, nb <= 64
  int v = (lane < nb) ? bsum[lane] : 0;
  int x = v;
  #pragma unroll
  for (int o = 1; o < 64; o <<= 1) {
    int t = __shfl_up(x, o, 64);
    if (lane >= o) x += t;
  }
  if (lane < nb) boffs[lane] = x - v;
  if (lane == 63) rowptr[n] = x;
}

__global__ void __launch_bounds__(256) k_scanC(const int* __restrict__ deg,
                                               const int* __restrict__ boffs,
                                               int* __restrict__ rowptr, int n) {
  __shared__ int wtot[4];
  int tid = threadIdx.x, lane = tid & 63, wv = tid >> 6;
  int i0 = blockIdx.x * 1024 + tid * 4;
  int4 v = make_int4(0, 0, 0, 0);
  if (i0 + 3 < n) v = *(const int4*)(deg + i0);
  else {
    if (i0 + 0 < n) v.x = deg[i0 + 0];
    if (i0 + 1 < n) v.y = deg[i0 + 1];
    if (i0 + 2 < n) v.z = deg[i0 + 2];
  }
  int s = v.x + v.y + v.z + v.w;
  int x = s;
  #pragma unroll
  for (int o = 1; o < 64; o <<= 1) {
    int t = __shfl_up(x, o, 64);
    if (lane >= o) x += t;
  }
  if (lane == 63) wtot[wv] = x;
  __syncthreads();
  int wexcl = 0;
  for (int k = 0; k < 4; k++) if (k < wv) wexcl += wtot[k];
  int excl = boffs[blockIdx.x] + wexcl + (x - s);
  int4 o4;
  o4.x = excl; o4.y = o4.x + v.x; o4.z = o4.y + v.y; o4.w = o4.z + v.z;
  if (i0 + 3 < n) *(int4*)(rowptr + i0) = o4;
  else {
    if (i0 + 0 < n) rowptr[i0 + 0] = o4.x;
    if (i0 + 1 < n) rowptr[i0 + 1] = o4.y;
    if (i0 + 2 < n) rowptr[i0 + 2] = o4.z;
  }
}

// permute (src, edge_attr) into CSR-by-dst order as packed int2
__global__ void k_fill(const int* __restrict__ src, const int* __restrict__ dst,
                       const float* __restrict__ ea_in, const int* __restrict__ rowptr,
                       int* __restrict__ cursor, int2* __restrict__ pairs, int E) {
  int e = blockIdx.x * blockDim.x + threadIdx.x;
  if (e < E) {
    int d = dst[e];
    int pos = rowptr[d] + atomicAdd(&cursor[d], 1);
    pairs[pos] = make_int2(src[e], __float_as_int(ea_in[e]));
  }
}

// xl = x @ Wl + bl ; xr = x @ Wr + br.  16 nodes/block, thread = (node, 4 cols).
template <int DIN>
__global__ void __launch_bounds__(256) k_transform(
    const float* __restrict__ x, const float* __restrict__ Wl, const float* __restrict__ bl,
    const float* __restrict__ Wr, const float* __restrict__ br,
    float* __restrict__ xl, float* __restrict__ xr, int nNodes) {
  __shared__ __align__(16) float sWl[DIN * 64];
  __shared__ __align__(16) float sWr[DIN * 64];
  __shared__ float sx[16][DIN + 1];
  int tid = threadIdx.x;
  for (int i = tid; i < DIN * 64; i += 256) { sWl[i] = Wl[i]; sWr[i] = Wr[i]; }
  int nb = blockIdx.x * 16;
  for (int i = tid; i < 16 * DIN; i += 256) {
    int ln = i / DIN, c = i % DIN;
    int g = nb + ln;
    sx[ln][c] = (g < nNodes) ? x[(size_t)g * DIN + c] : 0.f;
  }
  __syncthreads();
  int node = tid >> 4;          // 0..15
  int t4 = (tid & 15) * 4;      // col group
  float4 accl = *(const float4*)(bl + t4);
  float4 accr = *(const float4*)(br + t4);
  const float* xrow = sx[node];
  #pragma unroll 4
  for (int k = 0; k < DIN; k++) {
    float xv = xrow[k];
    float4 wl = *(const float4*)(sWl + k * 64 + t4);
    float4 wr = *(const float4*)(sWr + k * 64 + t4);
    accl.x = fmaf(xv, wl.x, accl.x); accl.y = fmaf(xv, wl.y, accl.y);
    accl.z = fmaf(xv, wl.z, accl.z); accl.w = fmaf(xv, wl.w, accl.w);
    accr.x = fmaf(xv, wr.x, accr.x); accr.y = fmaf(xv, wr.y, accr.y);
    accr.z = fmaf(xv, wr.z, accr.z); accr.w = fmaf(xv, wr.w, accr.w);
  }
  int g = nb + node;
  if (g < nNodes) {
    *(float4*)(xl + (size_t)g * 64 + t4) = accl;
    *(float4*)(xr + (size_t)g * 64 + t4) = accr;
  }
}

// Fused score + online softmax + aggregate. One wave per node, chunk = 32.
__global__ void __launch_bounds__(256, 4) k_edge(
    const float* __restrict__ xl, const float* __restrict__ xr,
    const int* __restrict__ rowptr, const int* __restrict__ pairs,  // int2 as int*
    const float* __restrict__ We, const float* __restrict__ att,
    const float* __restrict__ bo, float* __restrict__ xout, int nNodes) {
  __shared__ __align__(16) float tile[4][32 * 68];  // 8.7 KB per wave
  int lane = threadIdx.x & 63;
  int wv = rfl((int)(threadIdx.x >> 6));
  int n = rfl(blockIdx.x * 4 + wv);
  if (n >= nNodes) return;
  float* tw = tile[wv];
  int s0 = rfl(rowptr[n]);
  int s1 = rfl(rowptr[n + 1]);
  int e = lane >> 1, h = lane & 1;

  const float* xrp  = xr + (size_t)n * 64 + h * 32;  // per-lane half-row
  const float* Wep  = We + h * 32;
  const float* attp = att + h * 32;

  float m = -3.0e38f, d = 0.f, acc0 = 0.f, acc1 = 0.f;

  for (int kb = s0; kb < s1; kb += 32) {
    int cnt = rfl(min(32, s1 - kb));
    // pairs chunk: int2 elements [kb, kb+cnt) read as raw ints by 2*cnt lanes
    int raw = 0;
    if (lane < 2 * cnt) raw = pairs[2 * kb + lane];
    float ea = __int_as_float(__shfl(raw, lane | 1, 64));  // ea of my edge

    // ---- stage xl rows of this chunk into LDS (async DMA, 1 instr/row)
    for (int j = 0; j < cnt; ++j) {
      int s = __builtin_amdgcn_readlane(raw, 2 * j);
      row_to_lds(xl + (size_t)s * 64 + lane, tw + j * 68);
    }
    __builtin_amdgcn_s_waitcnt(0);

    // ---- score: lane (e,h) dots 32 channels of edge e, b128 tile reads
    const float* trow = tw + e * 68 + h * 32;
    float sc = 0.f;
    #pragma unroll
    for (int g = 0; g < 8; ++g) {
      float4 tv = *(const float4*)(trow + 4 * g);
      float4 xv = *(const float4*)(xrp + 4 * g);
      float4 wvv = *(const float4*)(Wep + 4 * g);
      float4 av = *(const float4*)(attp + 4 * g);
      float u;
      u = tv.x + fmaf(ea, wvv.x, xv.x); u = fmaxf(u, 0.2f * u); sc = fmaf(av.x, u, sc);
      u = tv.y + fmaf(ea, wvv.y, xv.y); u = fmaxf(u, 0.2f * u); sc = fmaf(av.y, u, sc);
      u = tv.z + fmaf(ea, wvv.z, xv.z); u = fmaxf(u, 0.2f * u); sc = fmaf(av.z, u, sc);
      u = tv.w + fmaf(ea, wvv.w, xv.w); u = fmaxf(u, 0.2f * u); sc = fmaf(av.w, u, sc);
    }
    sc += __shfl_xor(sc, 1, 64);           // combine channel halves: full dot
    sc = (e < cnt) ? sc : -3.0e38f;        // padded edges -> alpha = 0

    // ---- online softmax over 32 edges (parity-duplicated lanes)
    float mc = sc;
    #pragma unroll
    for (int o = 2; o <= 32; o <<= 1) mc = fmaxf(mc, __shfl_xor(mc, o, 64));
    float newm = fmaxf(m, mc);
    float r = expf(m - newm);              // 0 on first chunk, 1 if max unchanged
    float alpha = expf(sc - newm);
    float ds = alpha;
    #pragma unroll
    for (int o = 2; o <= 32; o <<= 1) ds += __shfl_xor(ds, o, 64);
    d = d * r + ds;
    acc0 *= r; acc1 *= r;
    m = newm;

    // ---- aggregate: lane = channel, fixed 32 iters (alpha=0 masks padding)
    #pragma unroll
    for (int j = 0; j < 32; j += 2) {
      acc0 = fmaf(readlane_f(alpha, 2 * j),       tw[j * 68 + lane],       acc0);
      acc1 = fmaf(readlane_f(alpha, 2 * (j + 1)), tw[(j + 1) * 68 + lane], acc1);
    }
  }

  float inv = 1.f / (d + 1e-16f);
  float out = (acc0 + acc1) * inv + bo[lane];
  xout[(size_t)n * 64 + lane] = fmaxf(out, 0.f);  // relu after every conv
}

__global__ void k_mean(const float* __restrict__ x, double* __restrict__ meanbuf, int nNodes) {
  __shared__ float sacc[256];
  int lane = threadIdx.x & 63;
  int wv = threadIdx.x >> 6;
  int gw = blockIdx.x * 4 + wv;
  int stride = gridDim.x * 4;
  float acc = 0.f;
  for (int n = gw; n < nNodes; n += stride) acc += x[(size_t)n * 64 + lane];
  sacc[threadIdx.x] = acc;
  __syncthreads();
  if (threadIdx.x < 64) {
    float a = sacc[threadIdx.x] + sacc[threadIdx.x + 64] + sacc[threadIdx.x + 128] + sacc[threadIdx.x + 192];
    atomicAdd(&meanbuf[lane], (double)a);
  }
}

__global__ void k_mlp(const double* __restrict__ meanbuf,
                      const float* __restrict__ Wm1, const float* __restrict__ bm1,
                      const float* __restrict__ Wm2, const float* __restrict__ bm2,
                      const float* __restrict__ Wm3, const float* __restrict__ bm3,
                      float* __restrict__ out, double invN) {
  __shared__ float xm[64];
  __shared__ float h1[32];
  __shared__ float h2[16];
  int t = threadIdx.x;
  xm[t] = (float)(meanbuf[t] * invN);
  __syncthreads();
  if (t < 32) {
    float a = bm1[t];
    for (int c = 0; c < 64; c++) a = fmaf(xm[c], Wm1[c * 32 + t], a);
    h1[t] = fmaxf(a, 0.f);
  }
  __syncthreads();
  if (t < 16) {
    float a = bm2[t];
    for (int c = 0; c < 32; c++) a = fmaf(h1[c], Wm2[c * 16 + t], a);
    h2[t] = fmaxf(a, 0.f);
  }
  __syncthreads();
  if (t == 0) {
    float a = bm3[0];
    for (int c = 0; c < 16; c++) a = fmaf(h2[c], Wm3[c], a);
    out[0] = a;
  }
}

extern "C" void kernel_launch(void* const* d_in, const int* in_sizes, int n_in,
                              void* d_out, int out_size, void* d_ws, size_t ws_size,
                              hipStream_t stream) {
  (void)n_in; (void)out_size; (void)ws_size;
  const int N = in_sizes[0] / 36;   // 50000
  const int E = in_sizes[1];        // 1600000

  const float* feat = (const float*)d_in[0];
  const float* eat  = (const float*)d_in[1];
  const int*   eidx = (const int*)d_in[2];
  const int* src = eidx;
  const int* dst = eidx + E;

  const float* L[4][7];  // Wl, bl, Wr, br, We, att, bo
  for (int l = 0; l < 4; l++)
    for (int j = 0; j < 7; j++) L[l][j] = (const float*)d_in[3 + l * 7 + j];
  const float* Wm1 = (const float*)d_in[31];
  const float* bm1 = (const float*)d_in[32];
  const float* Wm2 = (const float*)d_in[33];
  const float* bm2 = (const float*)d_in[34];
  const float* Wm3 = (const float*)d_in[35];
  const float* bm3 = (const float*)d_in[36];

  // workspace layout (512B aligned)
  char* ws = (char*)d_ws;
  size_t off = 0;
  auto alloc = [&](size_t bytes) {
    off = (off + 511) & ~(size_t)511;
    void* p = ws + off;
    off += bytes;
    return p;
  };
  int*    deg     = (int*)alloc((size_t)N * 4);
  int*    cursor  = (int*)alloc((size_t)N * 4);
  double* meanbuf = (double*)alloc(64 * 8);
  size_t zero_bytes = off;  // deg + cursor + meanbuf
  int*    rowptr  = (int*)alloc((size_t)(N + 1) * 4);
  int*    bsum    = (int*)alloc(64 * 4);
  int*    boffs   = (int*)alloc(64 * 4);
  int2*   pairs   = (int2*)alloc((size_t)E * 8);
  float*  xA      = (float*)alloc((size_t)N * 64 * 4);  // xl
  float*  xB      = (float*)alloc((size_t)N * 64 * 4);  // xr
  float*  xC      = (float*)alloc((size_t)N * 64 * 4);  // layer output / next input

  hipMemsetAsync(d_ws, 0, zero_bytes, stream);

  int egrid = (E + 255) / 256;
  int tgrid = (N + 15) / 16;  // k_transform: 16 nodes per 256-thr block
  int ngrid = (N + 3) / 4;    // k_edge: 4 nodes (waves) per 256-thr block
  int nb = (N + 1023) / 1024; // scan blocks (49 <= 64)

  k_hist<<<egrid, 256, 0, stream>>>(dst, deg, E);
  k_scanA<<<nb, 256, 0, stream>>>(deg, bsum, N);
  k_scanB<<<1, 64, 0, stream>>>(bsum, boffs, rowptr, nb, N);
  k_scanC<<<nb, 256, 0, stream>>>(deg, boffs, rowptr, N);
  k_fill<<<egrid, 256, 0, stream>>>(src, dst, eat, rowptr, cursor, pairs, E);

  for (int l = 0; l < 4; l++) {
    if (l == 0)
      k_transform<36><<<tgrid, 256, 0, stream>>>(feat, L[0][0], L[0][1], L[0][2], L[0][3], xA, xB, N);
    else
      k_transform<64><<<tgrid, 256, 0, stream>>>(xC, L[l][0], L[l][1], L[l][2], L[l][3], xA, xB, N);
    k_edge<<<ngrid, 256, 0, stream>>>(xA, xB, rowptr, (const int*)pairs,
                                      L[l][4], L[l][5], L[l][6], xC, N);
  }

  k_mean<<<256, 256, 0, stream>>>(xC, meanbuf, N);
  k_mlp<<<1, 64, 0, stream>>>(meanbuf, Wm1, bm1, Wm2, bm2, Wm3, bm3, (float*)d_out, 1.0 / (double)N);
}

// Round 4
// 684.340 us; speedup vs baseline: 2.2856x; 1.2779x over previous
//
#include <hip/hip_runtime.h>

// ---------------------------------------------------------------------------
// GATv2 x4 + MLP readout.  CSR-by-dst build once per call, then per layer:
//   k_transform: xl = x@Wl+bl, xr = x@Wr+br  (16 nodes/block, float4 acc)
//   k_edge: fused score + online-softmax + aggregate. One wave per NODE,
//     chunk = 16 edges.  Lane = (e = lane&15, q = lane>>4): each lane dots 16
//     channels of edge e from an LDS tile (stride 68, bank-balanced b128).
//     We/att (block) and xr row (wave) staged in LDS once -> ZERO VMEM in the
//     chunk loop besides the pairs load + 16 row DMAs (global_load_lds).
//     8 waves/SIMD (launch_bounds(256,8), 18.9 KB LDS/block) hide the drain.
// CSR scan is 3-kernel parallel.  Readout: f64-atomic mean + 1-block MLP.
// ---------------------------------------------------------------------------

__device__ __forceinline__ float readlane_f(float v, int l) {
  return __int_as_float(__builtin_amdgcn_readlane(__float_as_int(v), l));
}
__device__ __forceinline__ int rfl(int v) { return __builtin_amdgcn_readfirstlane(v); }

__device__ __forceinline__ void row_to_lds(const float* g, float* l) {
  __builtin_amdgcn_global_load_lds((const __attribute__((address_space(1))) void*)g,
                                   (__attribute__((address_space(3))) void*)l,
                                   4, 0, 0);
}

__global__ void k_hist(const int* __restrict__ dst, int* __restrict__ deg, int E) {
  int e = blockIdx.x * blockDim.x + threadIdx.x;
  if (e < E) atomicAdd(&deg[dst[e]], 1);
}

// ---- parallel exclusive scan over n ints: A (block sums), B (scan sums), C
__global__ void __launch_bounds__(256) k_scanA(const int* __restrict__ deg,
                                               int* __restrict__ bsum, int n) {
  __shared__ int ws[4];
  int tid = threadIdx.x, lane = tid & 63, wv = tid >> 6;
  int base = blockIdx.x * 1024 + tid;
  int s = 0;
  #pragma unroll
  for (int k = 0; k < 4; k++) {
    int i = base + k * 256;
    if (i < n) s += deg[i];
  }
  #pragma unroll
  for (int o = 32; o > 0; o >>= 1) s += __shfl_xor(s, o, 64);
  if (lane == 0) ws[wv] = s;
  __syncthreads();
  if (tid == 0) bsum[blockIdx.x] = ws[0] + ws[1] + ws[2] + ws[3];
}

__global__ void k_scanB(const int* __restrict__ bsum, int* __restrict__ boffs,
                        int* __restrict__ rowptr, int nb, int n) {
  int lane = threadIdx.x;  // 64 threads, nb <= 64
  int v = (lane < nb) ? bsum[lane] : 0;
  int x = v;
  #pragma unroll
  for (int o = 1; o < 64; o <<= 1) {
    int t = __shfl_up(x, o, 64);
    if (lane >= o) x += t;
  }
  if (lane < nb) boffs[lane] = x - v;
  if (lane == 63) rowptr[n] = x;
}

__global__ void __launch_bounds__(256) k_scanC(const int* __restrict__ deg,
                                               const int* __restrict__ boffs,
                                               int* __restrict__ rowptr, int n) {
  __shared__ int wtot[4];
  int tid = threadIdx.x, lane = tid & 63, wv = tid >> 6;
  int i0 = blockIdx.x * 1024 + tid * 4;
  int4 v = make_int4(0, 0, 0, 0);
  if (i0 + 3 < n) v = *(const int4*)(deg + i0);
  else {
    if (i0 + 0 < n) v.x = deg[i0 + 0];
    if (i0 + 1 < n) v.y = deg[i0 + 1];
    if (i0 + 2 < n) v.z = deg[i0 + 2];
  }
  int s = v.x + v.y + v.z + v.w;
  int x = s;
  #pragma unroll
  for (int o = 1; o < 64; o <<= 1) {
    int t = __shfl_up(x, o, 64);
    if (lane >= o) x += t;
  }
  if (lane == 63) wtot[wv] = x;
  __syncthreads();
  int wexcl = 0;
  for (int k = 0; k < 4; k++) if (k < wv) wexcl += wtot[k];
  int excl = boffs[blockIdx.x] + wexcl + (x - s);
  int4 o4;
  o4.x = excl; o4.y = o4.x + v.x; o4.z = o4.y + v.y; o4.w = o4.z + v.z;
  if (i0 + 3 < n) *(int4*)(rowptr + i0) = o4;
  else {
    if (i0 + 0 < n) rowptr[i0 + 0] = o4.x;
    if (i0 + 1 < n) rowptr[i0 + 1] = o4.y;
    if (i0 + 2 < n) rowptr[i0 + 2] = o4.z;
  }
}

// permute (src, edge_attr) into CSR-by-dst order as packed int2
__global__ void k_fill(const int* __restrict__ src, const int* __restrict__ dst,
                       const float* __restrict__ ea_in, const int* __restrict__ rowptr,
                       int* __restrict__ cursor, int2* __restrict__ pairs, int E) {
  int e = blockIdx.x * blockDim.x + threadIdx.x;
  if (e < E) {
    int d = dst[e];
    int pos = rowptr[d] + atomicAdd(&cursor[d], 1);
    pairs[pos] = make_int2(src[e], __float_as_int(ea_in[e]));
  }
}

// xl = x @ Wl + bl ; xr = x @ Wr + br.  16 nodes/block, thread = (node, 4 cols).
template <int DIN>
__global__ void __launch_bounds__(256) k_transform(
    const float* __restrict__ x, const float* __restrict__ Wl, const float* __restrict__ bl,
    const float* __restrict__ Wr, const float* __restrict__ br,
    float* __restrict__ xl, float* __restrict__ xr, int nNodes) {
  __shared__ __align__(16) float sWl[DIN * 64];
  __shared__ __align__(16) float sWr[DIN * 64];
  __shared__ float sx[16][DIN + 1];
  int tid = threadIdx.x;
  for (int i = tid; i < DIN * 64; i += 256) { sWl[i] = Wl[i]; sWr[i] = Wr[i]; }
  int nb = blockIdx.x * 16;
  for (int i = tid; i < 16 * DIN; i += 256) {
    int ln = i / DIN, c = i % DIN;
    int g = nb + ln;
    sx[ln][c] = (g < nNodes) ? x[(size_t)g * DIN + c] : 0.f;
  }
  __syncthreads();
  int node = tid >> 4;          // 0..15
  int t4 = (tid & 15) * 4;      // col group
  float4 accl = *(const float4*)(bl + t4);
  float4 accr = *(const float4*)(br + t4);
  const float* xrow = sx[node];
  #pragma unroll 4
  for (int k = 0; k < DIN; k++) {
    float xv = xrow[k];
    float4 wl = *(const float4*)(sWl + k * 64 + t4);
    float4 wr = *(const float4*)(sWr + k * 64 + t4);
    accl.x = fmaf(xv, wl.x, accl.x); accl.y = fmaf(xv, wl.y, accl.y);
    accl.z = fmaf(xv, wl.z, accl.z); accl.w = fmaf(xv, wl.w, accl.w);
    accr.x = fmaf(xv, wr.x, accr.x); accr.y = fmaf(xv, wr.y, accr.y);
    accr.z = fmaf(xv, wr.z, accr.z); accr.w = fmaf(xv, wr.w, accr.w);
  }
  int g = nb + node;
  if (g < nNodes) {
    *(float4*)(xl + (size_t)g * 64 + t4) = accl;
    *(float4*)(xr + (size_t)g * 64 + t4) = accr;
  }
}

// Fused score + online softmax + aggregate. One wave per node, chunk = 16.
__global__ void __launch_bounds__(256, 8) k_edge(
    const float* __restrict__ xl, const float* __restrict__ xr,
    const int* __restrict__ rowptr, const int* __restrict__ pairs,  // int2 as int*
    const float* __restrict__ We, const float* __restrict__ att,
    const float* __restrict__ bo, float* __restrict__ xout, int nNodes) {
  __shared__ __align__(16) float tile[4][16 * 68];  // 4.35 KB per wave
  __shared__ __align__(16) float sXr[4][64];
  __shared__ __align__(16) float sWe[64];
  __shared__ __align__(16) float sAtt[64];
  int tid = threadIdx.x;
  int lane = tid & 63;
  int wv = rfl(tid >> 6);
  int n = rfl(blockIdx.x * 4 + wv);
  if (tid < 64) { sWe[tid] = We[tid]; sAtt[tid] = att[tid]; }
  bool active = (n < nNodes);
  if (active) sXr[wv][lane] = xr[(size_t)n * 64 + lane];
  __syncthreads();
  if (!active) return;

  float* tw = tile[wv];
  int s0 = rfl(rowptr[n]);
  int s1 = rfl(rowptr[n + 1]);
  int e = lane & 15, q = lane >> 4;
  const float* xq = sXr[wv] + q * 16;
  const float* wq = sWe + q * 16;
  const float* aq = sAtt + q * 16;

  float m = -3.0e38f, d = 0.f, acc0 = 0.f, acc1 = 0.f;

  for (int kb = s0; kb < s1; kb += 16) {
    int cnt = rfl(min(16, s1 - kb));
    // pairs chunk: int2 elements [kb, kb+cnt) read raw by 2*cnt lanes
    int raw = 0;
    if (lane < 2 * cnt) raw = pairs[2 * kb + lane];
    float ea = __int_as_float(__shfl(raw, 2 * e + 1, 64));  // ea of my edge

    // ---- stage xl rows of this chunk into LDS (async DMA, 1 instr/row)
    for (int j = 0; j < cnt; ++j) {
      int s = __builtin_amdgcn_readlane(raw, 2 * j);
      row_to_lds(xl + (size_t)s * 64 + lane, tw + j * 68);
    }
    __builtin_amdgcn_s_waitcnt(0);

    // ---- score: lane (e,q) dots channels [16q,16q+16) of edge e.
    // All non-tile operands come from LDS (broadcast); no VMEM here.
    const float* trow = tw + e * 68 + q * 16;
    float sc = 0.f;
    #pragma unroll 2
    for (int g = 0; g < 4; ++g) {
      float4 tv = *(const float4*)(trow + 4 * g);
      float4 xv = *(const float4*)(xq + 4 * g);
      float4 wvv = *(const float4*)(wq + 4 * g);
      float4 av = *(const float4*)(aq + 4 * g);
      float u;
      u = tv.x + fmaf(ea, wvv.x, xv.x); u = fmaxf(u, 0.2f * u); sc = fmaf(av.x, u, sc);
      u = tv.y + fmaf(ea, wvv.y, xv.y); u = fmaxf(u, 0.2f * u); sc = fmaf(av.y, u, sc);
      u = tv.z + fmaf(ea, wvv.z, xv.z); u = fmaxf(u, 0.2f * u); sc = fmaf(av.z, u, sc);
      u = tv.w + fmaf(ea, wvv.w, xv.w); u = fmaxf(u, 0.2f * u); sc = fmaf(av.w, u, sc);
    }
    sc += __shfl_xor(sc, 16, 64);          // combine the 4 channel quarters
    sc += __shfl_xor(sc, 32, 64);
    sc = (e < cnt) ? sc : -3.0e38f;        // padded edges -> alpha = 0

    // ---- online softmax over 16 edges (quarter-duplicated lanes)
    float mc = sc;
    #pragma unroll
    for (int o = 1; o <= 8; o <<= 1) mc = fmaxf(mc, __shfl_xor(mc, o, 64));
    float newm = fmaxf(m, mc);
    float r = expf(m - newm);              // 0 on first chunk, 1 if max unchanged
    float alpha = expf(sc - newm);
    float ds = alpha;
    #pragma unroll
    for (int o = 1; o <= 8; o <<= 1) ds += __shfl_xor(ds, o, 64);
    d = d * r + ds;
    acc0 *= r; acc1 *= r;
    m = newm;

    // ---- aggregate: lane = channel, fixed 16 iters (alpha=0 masks padding)
    #pragma unroll 4
    for (int j = 0; j < 16; j += 2) {
      acc0 = fmaf(readlane_f(alpha, j),     tw[j * 68 + lane],       acc0);
      acc1 = fmaf(readlane_f(alpha, j + 1), tw[(j + 1) * 68 + lane], acc1);
    }
  }

  float inv = 1.f / (d + 1e-16f);
  float out = (acc0 + acc1) * inv + bo[lane];
  xout[(size_t)n * 64 + lane] = fmaxf(out, 0.f);  // relu after every conv
}

__global__ void k_mean(const float* __restrict__ x, double* __restrict__ meanbuf, int nNodes) {
  __shared__ float sacc[256];
  int lane = threadIdx.x & 63;
  int wv = threadIdx.x >> 6;
  int gw = blockIdx.x * 4 + wv;
  int stride = gridDim.x * 4;
  float acc = 0.f;
  for (int n = gw; n < nNodes; n += stride) acc += x[(size_t)n * 64 + lane];
  sacc[threadIdx.x] = acc;
  __syncthreads();
  if (threadIdx.x < 64) {
    float a = sacc[threadIdx.x] + sacc[threadIdx.x + 64] + sacc[threadIdx.x + 128] + sacc[threadIdx.x + 192];
    atomicAdd(&meanbuf[lane], (double)a);
  }
}

__global__ void k_mlp(const double* __restrict__ meanbuf,
                      const float* __restrict__ Wm1, const float* __restrict__ bm1,
                      const float* __restrict__ Wm2, const float* __restrict__ bm2,
                      const float* __restrict__ Wm3, const float* __restrict__ bm3,
                      float* __restrict__ out, double invN) {
  __shared__ float xm[64];
  __shared__ float h1[32];
  __shared__ float h2[16];
  int t = threadIdx.x;
  xm[t] = (float)(meanbuf[t] * invN);
  __syncthreads();
  if (t < 32) {
    float a = bm1[t];
    for (int c = 0; c < 64; c++) a = fmaf(xm[c], Wm1[c * 32 + t], a);
    h1[t] = fmaxf(a, 0.f);
  }
  __syncthreads();
  if (t < 16) {
    float a = bm2[t];
    for (int c = 0; c < 32; c++) a = fmaf(h1[c], Wm2[c * 16 + t], a);
    h2[t] = fmaxf(a, 0.f);
  }
  __syncthreads();
  if (t == 0) {
    float a = bm3[0];
    for (int c = 0; c < 16; c++) a = fmaf(h2[c], Wm3[c], a);
    out[0] = a;
  }
}

extern "C" void kernel_launch(void* const* d_in, const int* in_sizes, int n_in,
                              void* d_out, int out_size, void* d_ws, size_t ws_size,
                              hipStream_t stream) {
  (void)n_in; (void)out_size; (void)ws_size;
  const int N = in_sizes[0] / 36;   // 50000
  const int E = in_sizes[1];        // 1600000

  const float* feat = (const float*)d_in[0];
  const float* eat  = (const float*)d_in[1];
  const int*   eidx = (const int*)d_in[2];
  const int* src = eidx;
  const int* dst = eidx + E;

  const float* L[4][7];  // Wl, bl, Wr, br, We, att, bo
  for (int l = 0; l < 4; l++)
    for (int j = 0; j < 7; j++) L[l][j] = (const float*)d_in[3 + l * 7 + j];
  const float* Wm1 = (const float*)d_in[31];
  const float* bm1 = (const float*)d_in[32];
  const float* Wm2 = (const float*)d_in[33];
  const float* bm2 = (const float*)d_in[34];
  const float* Wm3 = (const float*)d_in[35];
  const float* bm3 = (const float*)d_in[36];

  // workspace layout (512B aligned)
  char* ws = (char*)d_ws;
  size_t off = 0;
  auto alloc = [&](size_t bytes) {
    off = (off + 511) & ~(size_t)511;
    void* p = ws + off;
    off += bytes;
    return p;
  };
  int*    deg     = (int*)alloc((size_t)N * 4);
  int*    cursor  = (int*)alloc((size_t)N * 4);
  double* meanbuf = (double*)alloc(64 * 8);
  size_t zero_bytes = off;  // deg + cursor + meanbuf
  int*    rowptr  = (int*)alloc((size_t)(N + 1) * 4);
  int*    bsum    = (int*)alloc(64 * 4);
  int*    boffs   = (int*)alloc(64 * 4);
  int2*   pairs   = (int2*)alloc((size_t)E * 8);
  float*  xA      = (float*)alloc((size_t)N * 64 * 4);  // xl
  float*  xB      = (float*)alloc((size_t)N * 64 * 4);  // xr
  float*  xC      = (float*)alloc((size_t)N * 64 * 4);  // layer output / next input

  hipMemsetAsync(d_ws, 0, zero_bytes, stream);

  int egrid = (E + 255) / 256;
  int tgrid = (N + 15) / 16;  // k_transform: 16 nodes per 256-thr block
  int ngrid = (N + 3) / 4;    // k_edge: 4 nodes (waves) per 256-thr block
  int nb = (N + 1023) / 1024; // scan blocks (49 <= 64)

  k_hist<<<egrid, 256, 0, stream>>>(dst, deg, E);
  k_scanA<<<nb, 256, 0, stream>>>(deg, bsum, N);
  k_scanB<<<1, 64, 0, stream>>>(bsum, boffs, rowptr, nb, N);
  k_scanC<<<nb, 256, 0, stream>>>(deg, boffs, rowptr, N);
  k_fill<<<egrid, 256, 0, stream>>>(src, dst, eat, rowptr, cursor, pairs, E);

  for (int l = 0; l < 4; l++) {
    if (l == 0)
      k_transform<36><<<tgrid, 256, 0, stream>>>(feat, L[0][0], L[0][1], L[0][2], L[0][3], xA, xB, N);
    else
      k_transform<64><<<tgrid, 256, 0, stream>>>(xC, L[l][0], L[l][1], L[l][2], L[l][3], xA, xB, N);
    k_edge<<<ngrid, 256, 0, stream>>>(xA, xB, rowptr, (const int*)pairs,
                                      L[l][4], L[l][5], L[l][6], xC, N);
  }

  k_mean<<<256, 256, 0, stream>>>(xC, meanbuf, N);
  k_mlp<<<1, 64, 0, stream>>>(meanbuf, Wm1, bm1, Wm2, bm2, Wm3, bm3, (float*)d_out, 1.0 / (double)N);
}